// Round 1
// baseline (1057.944 us; speedup 1.0000x reference)
//
#include <hip/hip_runtime.h>

// Problem constants (N=2048, L=512, K=16, DROP=2, DIM=1024)
#define NDIM 2048
#define LLEV 512
#define KDIM 16
#define HALF 1024

// ---------------------------------------------------------------------------
// Scan kernel: right = U_L ... U_1 (columns are independent!)
// 256 workgroups x 64 threads; each owns an 8-column slab of `right` in LDS.
// ---------------------------------------------------------------------------
__global__ __launch_bounds__(64) void scan_kernel(const float* __restrict__ O,
                                                  const int* __restrict__ idx,
                                                  float* __restrict__ right)
{
    __shared__ float slab[NDIM * 8];   // 64 KiB exactly
    const int lane = threadIdx.x;
    const int c0 = blockIdx.x * 8;
    const int c  = lane & 7;
    const int k1 = lane >> 3;          // 0..7
    const int k2 = k1 + 8;             // 8..15

    // init slab = identity columns c0..c0+7
    for (int r = lane; r < NDIM; r += 64) {
        *(float4*)&slab[r * 8]     = make_float4(0.f, 0.f, 0.f, 0.f);
        *(float4*)&slab[r * 8 + 4] = make_float4(0.f, 0.f, 0.f, 0.f);
    }
    __syncthreads();
    if (lane < 8) slab[(c0 + lane) * 8 + lane] = 1.0f;
    __syncthreads();

    int   rc[16]; float oa[16], ob[16]; int r1, r2;
    // prefetch level 0
    {
        #pragma unroll
        for (int j = 0; j < 16; ++j) rc[j] = idx[j];
        const float4* p1 = (const float4*)(O + k1 * 16);
        const float4* p2 = (const float4*)(O + k2 * 16);
        #pragma unroll
        for (int q = 0; q < 4; ++q) { *(float4*)&oa[q*4] = p1[q]; *(float4*)&ob[q*4] = p2[q]; }
        r1 = idx[k1]; r2 = idx[k2];
    }

    for (int l = 0; l < LLEV; ++l) {
        int rcc[16]; float a[16], b[16];
        const int w1 = r1, w2 = r2;
        #pragma unroll
        for (int j = 0; j < 16; ++j) { rcc[j] = rc[j]; a[j] = oa[j]; b[j] = ob[j]; }
        // prefetch next level (independent of LDS state)
        if (l + 1 < LLEV) {
            const int* ip = idx + (l + 1) * 16;
            #pragma unroll
            for (int j = 0; j < 16; ++j) rc[j] = ip[j];
            const float4* p1 = (const float4*)(O + (l + 1) * 256 + k1 * 16);
            const float4* p2 = (const float4*)(O + (l + 1) * 256 + k2 * 16);
            #pragma unroll
            for (int q = 0; q < 4; ++q) { *(float4*)&oa[q*4] = p1[q]; *(float4*)&ob[q*4] = p2[q]; }
            r1 = ip[k1]; r2 = ip[k2];
        }
        // read the 16-row block for this lane's column
        float blk[16];
        #pragma unroll
        for (int j = 0; j < 16; ++j) blk[j] = slab[rcc[j] * 8 + c];
        float s1 = 0.f, s2 = 0.f;
        #pragma unroll
        for (int j = 0; j < 16; ++j) { s1 += a[j] * blk[j]; s2 += b[j] * blk[j]; }
        __syncthreads();   // all reads done before any write
        slab[w1 * 8 + c] = s1;
        slab[w2 * 8 + c] = s2;
        __syncthreads();   // writes visible before next level's reads
    }

    for (int r = lane; r < NDIM; r += 64) {
        *(float4*)(right + (size_t)r * NDIM + c0)     = *(float4*)&slab[r * 8];
        *(float4*)(right + (size_t)r * NDIM + c0 + 4) = *(float4*)&slab[r * 8 + 4];
    }
}

// ---------------------------------------------------------------------------
// Tiled fp32 gemms: 64x64 tile, BK=16, 256 threads, 4x4 micro-tile.
// ---------------------------------------------------------------------------
// NT: C[m,n] = sum_k A[rA(m),k] * B[rB(n),k]
__global__ __launch_bounds__(256) void gemm_nt(const float* __restrict__ A, int lda,
                                               const int* __restrict__ ridxA,
                                               const float* __restrict__ B, int ldb,
                                               const int* __restrict__ ridxB,
                                               float* __restrict__ C, int ldc, int Kk)
{
    __shared__ float As[16][68];
    __shared__ float Bs[16][68];
    const int tid = threadIdx.x;
    const int tx = tid & 15, ty = tid >> 4;
    const int m0 = blockIdx.x * 64, n0 = blockIdx.y * 64;
    const int li = tid >> 2;          // 0..63
    const int lk = (tid & 3) * 4;     // 0,4,8,12
    int rowA = m0 + li; if (ridxA) rowA = ridxA[rowA];
    int rowB = n0 + li; if (ridxB) rowB = ridxB[rowB];
    const float* pA = A + (size_t)rowA * lda + lk;
    const float* pB = B + (size_t)rowB * ldb + lk;
    float acc[4][4] = {};
    for (int k0 = 0; k0 < Kk; k0 += 16) {
        float4 a4 = *(const float4*)(pA + k0);
        float4 b4 = *(const float4*)(pB + k0);
        As[lk + 0][li] = a4.x; As[lk + 1][li] = a4.y; As[lk + 2][li] = a4.z; As[lk + 3][li] = a4.w;
        Bs[lk + 0][li] = b4.x; Bs[lk + 1][li] = b4.y; Bs[lk + 2][li] = b4.z; Bs[lk + 3][li] = b4.w;
        __syncthreads();
        #pragma unroll
        for (int kk = 0; kk < 16; ++kk) {
            float4 av = *(const float4*)&As[kk][ty * 4];
            float4 bv = *(const float4*)&Bs[kk][tx * 4];
            float a[4] = {av.x, av.y, av.z, av.w};
            float b[4] = {bv.x, bv.y, bv.z, bv.w};
            #pragma unroll
            for (int i = 0; i < 4; ++i)
                #pragma unroll
                for (int j = 0; j < 4; ++j) acc[i][j] += a[i] * b[j];
        }
        __syncthreads();
    }
    #pragma unroll
    for (int i = 0; i < 4; ++i) {
        float4 v = make_float4(acc[i][0], acc[i][1], acc[i][2], acc[i][3]);
        *(float4*)(C + (size_t)(m0 + ty * 4 + i) * ldc + n0 + tx * 4) = v;
    }
}

// NN: C[m,n] = sum_k A[m,k] * B[k,n]
__global__ __launch_bounds__(256) void gemm_nn(const float* __restrict__ A, int lda,
                                               const float* __restrict__ B, int ldb,
                                               float* __restrict__ C, int ldc, int Kk)
{
    __shared__ float As[16][68];
    __shared__ float Bs[16][68];
    const int tid = threadIdx.x;
    const int tx = tid & 15, ty = tid >> 4;
    const int m0 = blockIdx.x * 64, n0 = blockIdx.y * 64;
    const int li = tid >> 2;
    const int lk = (tid & 3) * 4;
    const int bk = tid >> 4;          // 0..15
    const int bn = (tid & 15) * 4;    // 0..60
    const float* pA = A + (size_t)(m0 + li) * lda + lk;
    float acc[4][4] = {};
    for (int k0 = 0; k0 < Kk; k0 += 16) {
        float4 a4 = *(const float4*)(pA + k0);
        float4 b4 = *(const float4*)(B + (size_t)(k0 + bk) * ldb + n0 + bn);
        As[lk + 0][li] = a4.x; As[lk + 1][li] = a4.y; As[lk + 2][li] = a4.z; As[lk + 3][li] = a4.w;
        *(float4*)&Bs[bk][bn] = b4;
        __syncthreads();
        #pragma unroll
        for (int kk = 0; kk < 16; ++kk) {
            float4 av = *(const float4*)&As[kk][ty * 4];
            float4 bv = *(const float4*)&Bs[kk][tx * 4];
            float a[4] = {av.x, av.y, av.z, av.w};
            float b[4] = {bv.x, bv.y, bv.z, bv.w};
            #pragma unroll
            for (int i = 0; i < 4; ++i)
                #pragma unroll
                for (int j = 0; j < 4; ++j) acc[i][j] += a[i] * b[j];
        }
        __syncthreads();
    }
    #pragma unroll
    for (int i = 0; i < 4; ++i) {
        float4 v = make_float4(acc[i][0], acc[i][1], acc[i][2], acc[i][3]);
        *(float4*)(C + (size_t)(m0 + ty * 4 + i) * ldc + n0 + tx * 4) = v;
    }
}

// A_rec[m,n] = sum_t H[t,m] * G[t,n];  H = [fw; mw], G = [W1; dm.*mw]  (TN)
__global__ __launch_bounds__(256) void arec_kernel(const float* __restrict__ fw,
                                                   const float* __restrict__ mw,
                                                   const float* __restrict__ W1,
                                                   const float* __restrict__ dm,
                                                   float* __restrict__ C)
{
    __shared__ float As[16][68];
    __shared__ float Bs[16][68];
    const int tid = threadIdx.x;
    const int tx = tid & 15, ty = tid >> 4;
    const int m0 = blockIdx.x * 64, n0 = blockIdx.y * 64;
    const int bk = tid >> 4;          // tile row (t)
    const int bn = (tid & 15) * 4;    // tile col
    float acc[4][4] = {};
    for (int t0 = 0; t0 < NDIM; t0 += 16) {
        const int t = t0 + bk;
        const float* Hrow; const float* Grow; float gs;
        if (t < HALF) { Hrow = fw + (size_t)t * NDIM; Grow = W1 + (size_t)t * NDIM; gs = 1.f; }
        else          { Hrow = mw + (size_t)(t - HALF) * NDIM; Grow = Hrow; gs = dm[t - HALF]; }
        float4 a4 = *(const float4*)(Hrow + m0 + bn);
        float4 b4 = *(const float4*)(Grow + n0 + bn);
        b4.x *= gs; b4.y *= gs; b4.z *= gs; b4.w *= gs;
        *(float4*)&As[bk][bn] = a4;
        *(float4*)&Bs[bk][bn] = b4;
        __syncthreads();
        #pragma unroll
        for (int kk = 0; kk < 16; ++kk) {
            float4 av = *(const float4*)&As[kk][ty * 4];
            float4 bv = *(const float4*)&Bs[kk][tx * 4];
            float a[4] = {av.x, av.y, av.z, av.w};
            float b[4] = {bv.x, bv.y, bv.z, bv.w};
            #pragma unroll
            for (int i = 0; i < 4; ++i)
                #pragma unroll
                for (int j = 0; j < 4; ++j) acc[i][j] += a[i] * b[j];
        }
        __syncthreads();
    }
    #pragma unroll
    for (int i = 0; i < 4; ++i) {
        float4 v = make_float4(acc[i][0], acc[i][1], acc[i][2], acc[i][3]);
        *(float4*)(C + (size_t)(m0 + ty * 4 + i) * NDIM + n0 + tx * 4) = v;
    }
}

// ---------------------------------------------------------------------------
// Small helpers
// ---------------------------------------------------------------------------
__global__ __launch_bounds__(256) void diag_kernel(const float* __restrict__ P,
                                                   const float* __restrict__ R,
                                                   float* __restrict__ diag_all)
{
    __shared__ float red[256];
    const int i = blockIdx.x;
    const float4* p4 = (const float4*)(P + (size_t)i * NDIM);
    const float4* r4 = (const float4*)(R + (size_t)i * NDIM);
    float s = 0.f;
    for (int k = threadIdx.x; k < NDIM / 4; k += 256) {
        float4 a = p4[k], b = r4[k];
        s += a.x * b.x + a.y * b.y + a.z * b.z + a.w * b.w;
    }
    red[threadIdx.x] = s;
    __syncthreads();
    for (int off = 128; off > 0; off >>= 1) {
        if (threadIdx.x < off) red[threadIdx.x] += red[threadIdx.x + off];
        __syncthreads();
    }
    if (threadIdx.x == 0) diag_all[i] = red[0];
}

__global__ void prep_kernel(const int* __restrict__ act, const int* __restrict__ inact,
                            const float* __restrict__ diag_all,
                            int* __restrict__ inv, float* __restrict__ dm)
{
    const int t = threadIdx.x;   // 1024 threads
    inv[t] = -1;
    inv[t + HALF] = -1;
    __syncthreads();
    inv[act[t]] = t;
    dm[t] = diag_all[inact[t]];
}

__global__ __launch_bounds__(256) void build_D(const float* __restrict__ Daa,
                                               const float* __restrict__ diag_all,
                                               const int* __restrict__ inv,
                                               float* __restrict__ D)
{
    const int e = blockIdx.x * 256 + threadIdx.x;
    const int i = e >> 11, j = e & (NDIM - 1);
    const int ii = inv[i], jj = inv[j];
    float v = 0.f;
    if (ii >= 0 && jj >= 0) v = Daa[ii * HALF + jj];
    if (i == j) v = diag_all[i];
    D[e] = v;
}

__global__ __launch_bounds__(256) void mc_kernel(const float* __restrict__ dm,
                                                 float* __restrict__ mc)
{
    const int e = blockIdx.x * 256 + threadIdx.x;
    const int t = e >> 10, s = e & (HALF - 1);
    mc[e] = (t == s) ? dm[t] : 0.f;
}

__global__ __launch_bounds__(512) void gather_rows(const float* __restrict__ R,
                                                   const int* __restrict__ ridx,
                                                   float* __restrict__ outp)
{
    const int r = blockIdx.x;
    const int c = threadIdx.x * 4;
    *(float4*)(outp + (size_t)r * NDIM + c) =
        *(const float4*)(R + (size_t)ridx[r] * NDIM + c);
}

// ---------------------------------------------------------------------------
extern "C" void kernel_launch(void* const* d_in, const int* in_sizes, int n_in,
                              void* d_out, int out_size, void* d_ws, size_t ws_size,
                              hipStream_t stream)
{
    (void)in_sizes; (void)n_in; (void)out_size; (void)ws_size;
    const float* A     = (const float*)d_in[0];
    const float* O     = (const float*)d_in[1];
    const int*   idx   = (const int*)d_in[2];
    const int*   act   = (const int*)d_in[3];
    const int*   inact = (const int*)d_in[4];

    float* out = (float*)d_out;
    const size_t NN = (size_t)NDIM * NDIM;
    float* A_rec = out;                       // also scratch for P = R@A
    float* right = out + NN;
    float* D     = out + 2 * NN;              // also scratch for W1 (first 8 MB)
    float* mc    = out + 3 * NN;
    float* fc    = mc + (size_t)HALF * HALF;  // Daa
    float* mw    = fc + (size_t)HALF * HALF;
    float* fw    = mw + (size_t)HALF * NDIM;

    char*  w        = (char*)d_ws;
    float* diag_all = (float*)w;              // 2048 f
    float* dm       = (float*)(w + 8192);     // 1024 f
    int*   inv      = (int*)(w + 12288);      // 2048 i

    // 1. right = product of U's (column-parallel scan)
    scan_kernel<<<256, 64, 0, stream>>>(O, idx, right);
    // 2. wavelets (row gathers; fw doubles as Ra, mw as Mi)
    gather_rows<<<1024, 512, 0, stream>>>(right, act, fw);
    gather_rows<<<1024, 512, 0, stream>>>(right, inact, mw);
    // 3. P = R @ A  (A symmetric -> NT)   [into A_rec slot]
    gemm_nt<<<dim3(32, 32), 256, 0, stream>>>(right, NDIM, nullptr, A, NDIM, nullptr,
                                              A_rec, NDIM, NDIM);
    // 4. diag_all[i] = P[i] . R[i]
    diag_kernel<<<2048, 256, 0, stream>>>(A_rec, right, diag_all);
    // 5. inv map + dm
    prep_kernel<<<1, 1024, 0, stream>>>(act, inact, diag_all, inv, dm);
    // 6. Daa[i,j] = P[a_i] . R[a_j]   [into father_coefficients slot]
    gemm_nt<<<dim3(16, 16), 256, 0, stream>>>(A_rec, NDIM, act, right, NDIM, act,
                                              fc, HALF, NDIM);
    // 7. W1 = Daa @ Ra (=fw)   [into D slot]
    gemm_nn<<<dim3(16, 32), 256, 0, stream>>>(fc, HALF, fw, NDIM, D, NDIM, HALF);
    // 8. A_rec = H^T G (overwrites P — safe, P consumed in 4 & 6)
    arec_kernel<<<dim3(32, 32), 256, 0, stream>>>(fw, mw, D, dm, A_rec);
    // 9. D (overwrites W1 — safe, consumed in 8)
    build_D<<<16384, 256, 0, stream>>>(fc, diag_all, inv, D);
    // 10. mother_coefficients = diag(dm)
    mc_kernel<<<4096, 256, 0, stream>>>(dm, mc);
}

// Round 2
// 1043.434 us; speedup vs baseline: 1.0139x; 1.0139x over previous
//
#include <hip/hip_runtime.h>

// Problem constants (N=2048, L=512, K=16, DROP=2, DIM=1024)
#define NDIM 2048
#define LLEV 512
#define KDIM 16
#define HALF 1024

// ---------------------------------------------------------------------------
// Scan kernel v2: right = U_L ... U_1 (columns independent).
// 256 blocks x 64 threads (ONE wave) x 8 columns, slab in LDS (64 KiB).
// Single-wave lockstep => NO barriers: all lanes' ds_reads of level l are
// program-ordered before any lane's ds_write of level l, and before level
// l+1's reads. Removing the barriers also removes the vmcnt(0) drains that
// were defeating the O/idx prefetch (R1: 1266 cyc/level).
// ---------------------------------------------------------------------------
__global__ __launch_bounds__(64) void scan_kernel(const float* __restrict__ O,
                                                  const int* __restrict__ idx,
                                                  float* __restrict__ right)
{
    __shared__ float slab[NDIM * 8];   // 64 KiB: slab[row*8 + col]
    const int lane = threadIdx.x;
    const int c0 = blockIdx.x * 8;
    const int k  = lane >> 2;          // 0..15  (row of O)
    const int c2 = (lane & 3) * 2;     // column pair 0,2,4,6

    // init slab = identity columns c0..c0+7 (single wave: ordering by program order)
    for (int r = lane; r < NDIM; r += 64) {
        *(float4*)&slab[r * 8]     = make_float4(0.f, 0.f, 0.f, 0.f);
        *(float4*)&slab[r * 8 + 4] = make_float4(0.f, 0.f, 0.f, 0.f);
    }
    if (lane < 8) slab[(c0 + lane) * 8 + lane] = 1.0f;

    // prefetch level 0
    int rows[16]; float a[16]; int wrow;
    #pragma unroll
    for (int j = 0; j < 16; ++j) rows[j] = idx[j];
    {
        const float4* p4 = (const float4*)(O + k * 16);
        #pragma unroll
        for (int q = 0; q < 4; ++q) *(float4*)&a[q * 4] = p4[q];
    }
    wrow = idx[k];

    for (int l = 0; l < LLEV; ++l) {
        int rr[16]; float aa[16];
        const int wr = wrow;
        #pragma unroll
        for (int j = 0; j < 16; ++j) { rr[j] = rows[j]; aa[j] = a[j]; }
        // prefetch next level (overlaps with LDS work below — no barrier drain)
        if (l + 1 < LLEV) {
            const int* ip = idx + (l + 1) * 16;
            #pragma unroll
            for (int j = 0; j < 16; ++j) rows[j] = ip[j];
            const float4* p4 = (const float4*)(O + (l + 1) * 256 + k * 16);
            #pragma unroll
            for (int q = 0; q < 4; ++q) *(float4*)&a[q * 4] = p4[q];
            wrow = ip[k];
        }
        // lane (k, c2): new row idx[k] at cols c2,c2+1 = dot(O[k,:], old 16 rows)
        float sx = 0.f, sy = 0.f;
        #pragma unroll
        for (int j = 0; j < 16; ++j) {
            float2 v = *(float2*)&slab[rr[j] * 8 + c2];   // uniform row -> broadcast
            sx += aa[j] * v.x;
            sy += aa[j] * v.y;
        }
        *(float2*)&slab[wr * 8 + c2] = make_float2(sx, sy);
    }

    // write out 8-column slab
    for (int r0 = 0; r0 < NDIM; r0 += 32) {
        const int r = r0 + (lane >> 1);
        const int h = (lane & 1) * 4;
        *(float4*)(right + (size_t)r * NDIM + c0 + h) = *(float4*)&slab[r * 8 + h];
    }
}

// ---------------------------------------------------------------------------
// 128x128-tile fp32 NT gemm: C[m,n] = sum_k A[m,k]*B[n,k]. 256 thr, 8x8 micro.
// BK=16, register-prefetch pipeline. lda = ldb = Kk assumed.
// ---------------------------------------------------------------------------
__global__ __launch_bounds__(256) void gemm128_nt(const float* __restrict__ A,
                                                  const float* __restrict__ B,
                                                  float* __restrict__ C,
                                                  int Kk, int ldc)
{
    __shared__ float As[16][132];
    __shared__ float Bs[16][132];
    const int tid = threadIdx.x;
    const int tx = tid & 15, ty = tid >> 4;
    const int m0 = blockIdx.x * 128, n0 = blockIdx.y * 128;
    const int row = tid >> 1;          // 0..127
    const int kc  = (tid & 1) * 8;     // 0 or 8
    const float* pA = A + (size_t)(m0 + row) * Kk + kc;
    const float* pB = B + (size_t)(n0 + row) * Kk + kc;

    float4 a0 = *(const float4*)(pA);
    float4 a1 = *(const float4*)(pA + 4);
    float4 b0 = *(const float4*)(pB);
    float4 b1 = *(const float4*)(pB + 4);

    float acc[8][8] = {};
    for (int k0 = 0; k0 < Kk; k0 += 16) {
        __syncthreads();
        As[kc+0][row]=a0.x; As[kc+1][row]=a0.y; As[kc+2][row]=a0.z; As[kc+3][row]=a0.w;
        As[kc+4][row]=a1.x; As[kc+5][row]=a1.y; As[kc+6][row]=a1.z; As[kc+7][row]=a1.w;
        Bs[kc+0][row]=b0.x; Bs[kc+1][row]=b0.y; Bs[kc+2][row]=b0.z; Bs[kc+3][row]=b0.w;
        Bs[kc+4][row]=b1.x; Bs[kc+5][row]=b1.y; Bs[kc+6][row]=b1.z; Bs[kc+7][row]=b1.w;
        __syncthreads();
        if (k0 + 16 < Kk) {
            a0 = *(const float4*)(pA + k0 + 16);
            a1 = *(const float4*)(pA + k0 + 20);
            b0 = *(const float4*)(pB + k0 + 16);
            b1 = *(const float4*)(pB + k0 + 20);
        }
        #pragma unroll
        for (int kk = 0; kk < 16; ++kk) {
            float a[8], b[8];
            *(float4*)&a[0] = *(const float4*)&As[kk][ty * 8];
            *(float4*)&a[4] = *(const float4*)&As[kk][ty * 8 + 4];
            *(float4*)&b[0] = *(const float4*)&Bs[kk][tx * 8];
            *(float4*)&b[4] = *(const float4*)&Bs[kk][tx * 8 + 4];
            #pragma unroll
            for (int i = 0; i < 8; ++i)
                #pragma unroll
                for (int j = 0; j < 8; ++j) acc[i][j] += a[i] * b[j];
        }
    }
    #pragma unroll
    for (int i = 0; i < 8; ++i) {
        float* cp = C + (size_t)(m0 + ty * 8 + i) * ldc + n0 + tx * 8;
        *(float4*)(cp)     = make_float4(acc[i][0], acc[i][1], acc[i][2], acc[i][3]);
        *(float4*)(cp + 4) = make_float4(acc[i][4], acc[i][5], acc[i][6], acc[i][7]);
    }
}

// ---------------------------------------------------------------------------
// 128x128-tile TN: A_rec[m,n] = sum_t H[t,m]*G[t,n]; H=[fw;mw], G=[W1; dm.*mw]
// ---------------------------------------------------------------------------
__global__ __launch_bounds__(256) void arec128(const float* __restrict__ fw,
                                               const float* __restrict__ mw,
                                               const float* __restrict__ W1,
                                               const float* __restrict__ dm,
                                               float* __restrict__ C)
{
    __shared__ float As[16][132];
    __shared__ float Bs[16][132];
    const int tid = threadIdx.x;
    const int tx = tid & 15, ty = tid >> 4;
    const int m0 = blockIdx.x * 128, n0 = blockIdx.y * 128;
    const int bk = tid >> 4;           // 0..15 (t within tile)
    const int bn = (tid & 15) * 8;     // 0..120

    auto load_t = [&](int t, float4& h0, float4& h1, float4& g0, float4& g1) {
        const float* Hrow; const float* Grow; float gs;
        if (t < HALF) { Hrow = fw + (size_t)t * NDIM; Grow = W1 + (size_t)t * NDIM; gs = 1.f; }
        else          { Hrow = mw + (size_t)(t - HALF) * NDIM; Grow = Hrow; gs = dm[t - HALF]; }
        h0 = *(const float4*)(Hrow + m0 + bn);
        h1 = *(const float4*)(Hrow + m0 + bn + 4);
        g0 = *(const float4*)(Grow + n0 + bn);
        g1 = *(const float4*)(Grow + n0 + bn + 4);
        g0.x*=gs; g0.y*=gs; g0.z*=gs; g0.w*=gs;
        g1.x*=gs; g1.y*=gs; g1.z*=gs; g1.w*=gs;
    };

    float4 h0, h1, g0, g1;
    load_t(bk, h0, h1, g0, g1);

    float acc[8][8] = {};
    for (int t0 = 0; t0 < NDIM; t0 += 16) {
        __syncthreads();
        *(float4*)&As[bk][bn]     = h0;
        *(float4*)&As[bk][bn + 4] = h1;
        *(float4*)&Bs[bk][bn]     = g0;
        *(float4*)&Bs[bk][bn + 4] = g1;
        __syncthreads();
        if (t0 + 16 < NDIM) load_t(t0 + 16 + bk, h0, h1, g0, g1);
        #pragma unroll
        for (int kk = 0; kk < 16; ++kk) {
            float a[8], b[8];
            *(float4*)&a[0] = *(const float4*)&As[kk][ty * 8];
            *(float4*)&a[4] = *(const float4*)&As[kk][ty * 8 + 4];
            *(float4*)&b[0] = *(const float4*)&Bs[kk][tx * 8];
            *(float4*)&b[4] = *(const float4*)&Bs[kk][tx * 8 + 4];
            #pragma unroll
            for (int i = 0; i < 8; ++i)
                #pragma unroll
                for (int j = 0; j < 8; ++j) acc[i][j] += a[i] * b[j];
        }
    }
    #pragma unroll
    for (int i = 0; i < 8; ++i) {
        float* cp = C + (size_t)(m0 + ty * 8 + i) * NDIM + n0 + tx * 8;
        *(float4*)(cp)     = make_float4(acc[i][0], acc[i][1], acc[i][2], acc[i][3]);
        *(float4*)(cp + 4) = make_float4(acc[i][4], acc[i][5], acc[i][6], acc[i][7]);
    }
}

// ---------------------------------------------------------------------------
// 64x64-tile fp32 gemms (kept for the small products: Daa NT, W1 NN)
// ---------------------------------------------------------------------------
__global__ __launch_bounds__(256) void gemm_nt(const float* __restrict__ A, int lda,
                                               const int* __restrict__ ridxA,
                                               const float* __restrict__ B, int ldb,
                                               const int* __restrict__ ridxB,
                                               float* __restrict__ C, int ldc, int Kk)
{
    __shared__ float As[16][68];
    __shared__ float Bs[16][68];
    const int tid = threadIdx.x;
    const int tx = tid & 15, ty = tid >> 4;
    const int m0 = blockIdx.x * 64, n0 = blockIdx.y * 64;
    const int li = tid >> 2;
    const int lk = (tid & 3) * 4;
    int rowA = m0 + li; if (ridxA) rowA = ridxA[rowA];
    int rowB = n0 + li; if (ridxB) rowB = ridxB[rowB];
    const float* pA = A + (size_t)rowA * lda + lk;
    const float* pB = B + (size_t)rowB * ldb + lk;
    float acc[4][4] = {};
    for (int k0 = 0; k0 < Kk; k0 += 16) {
        float4 a4 = *(const float4*)(pA + k0);
        float4 b4 = *(const float4*)(pB + k0);
        As[lk + 0][li] = a4.x; As[lk + 1][li] = a4.y; As[lk + 2][li] = a4.z; As[lk + 3][li] = a4.w;
        Bs[lk + 0][li] = b4.x; Bs[lk + 1][li] = b4.y; Bs[lk + 2][li] = b4.z; Bs[lk + 3][li] = b4.w;
        __syncthreads();
        #pragma unroll
        for (int kk = 0; kk < 16; ++kk) {
            float4 av = *(const float4*)&As[kk][ty * 4];
            float4 bv = *(const float4*)&Bs[kk][tx * 4];
            float a[4] = {av.x, av.y, av.z, av.w};
            float b[4] = {bv.x, bv.y, bv.z, bv.w};
            #pragma unroll
            for (int i = 0; i < 4; ++i)
                #pragma unroll
                for (int j = 0; j < 4; ++j) acc[i][j] += a[i] * b[j];
        }
        __syncthreads();
    }
    #pragma unroll
    for (int i = 0; i < 4; ++i) {
        float4 v = make_float4(acc[i][0], acc[i][1], acc[i][2], acc[i][3]);
        *(float4*)(C + (size_t)(m0 + ty * 4 + i) * ldc + n0 + tx * 4) = v;
    }
}

__global__ __launch_bounds__(256) void gemm_nn(const float* __restrict__ A, int lda,
                                               const float* __restrict__ B, int ldb,
                                               float* __restrict__ C, int ldc, int Kk)
{
    __shared__ float As[16][68];
    __shared__ float Bs[16][68];
    const int tid = threadIdx.x;
    const int tx = tid & 15, ty = tid >> 4;
    const int m0 = blockIdx.x * 64, n0 = blockIdx.y * 64;
    const int li = tid >> 2;
    const int lk = (tid & 3) * 4;
    const int bk = tid >> 4;
    const int bn = (tid & 15) * 4;
    const float* pA = A + (size_t)(m0 + li) * lda + lk;
    float acc[4][4] = {};
    for (int k0 = 0; k0 < Kk; k0 += 16) {
        float4 a4 = *(const float4*)(pA + k0);
        float4 b4 = *(const float4*)(B + (size_t)(k0 + bk) * ldb + n0 + bn);
        As[lk + 0][li] = a4.x; As[lk + 1][li] = a4.y; As[lk + 2][li] = a4.z; As[lk + 3][li] = a4.w;
        *(float4*)&Bs[bk][bn] = b4;
        __syncthreads();
        #pragma unroll
        for (int kk = 0; kk < 16; ++kk) {
            float4 av = *(const float4*)&As[kk][ty * 4];
            float4 bv = *(const float4*)&Bs[kk][tx * 4];
            float a[4] = {av.x, av.y, av.z, av.w};
            float b[4] = {bv.x, bv.y, bv.z, bv.w};
            #pragma unroll
            for (int i = 0; i < 4; ++i)
                #pragma unroll
                for (int j = 0; j < 4; ++j) acc[i][j] += a[i] * b[j];
        }
        __syncthreads();
    }
    #pragma unroll
    for (int i = 0; i < 4; ++i) {
        float4 v = make_float4(acc[i][0], acc[i][1], acc[i][2], acc[i][3]);
        *(float4*)(C + (size_t)(m0 + ty * 4 + i) * ldc + n0 + tx * 4) = v;
    }
}

// ---------------------------------------------------------------------------
// Small helpers (unchanged from R1)
// ---------------------------------------------------------------------------
__global__ __launch_bounds__(256) void diag_kernel(const float* __restrict__ P,
                                                   const float* __restrict__ R,
                                                   float* __restrict__ diag_all)
{
    __shared__ float red[256];
    const int i = blockIdx.x;
    const float4* p4 = (const float4*)(P + (size_t)i * NDIM);
    const float4* r4 = (const float4*)(R + (size_t)i * NDIM);
    float s = 0.f;
    for (int kq = threadIdx.x; kq < NDIM / 4; kq += 256) {
        float4 a = p4[kq], b = r4[kq];
        s += a.x * b.x + a.y * b.y + a.z * b.z + a.w * b.w;
    }
    red[threadIdx.x] = s;
    __syncthreads();
    for (int off = 128; off > 0; off >>= 1) {
        if (threadIdx.x < off) red[threadIdx.x] += red[threadIdx.x + off];
        __syncthreads();
    }
    if (threadIdx.x == 0) diag_all[i] = red[0];
}

__global__ void prep_kernel(const int* __restrict__ act, const int* __restrict__ inact,
                            const float* __restrict__ diag_all,
                            int* __restrict__ inv, float* __restrict__ dm)
{
    const int t = threadIdx.x;
    inv[t] = -1;
    inv[t + HALF] = -1;
    __syncthreads();
    inv[act[t]] = t;
    dm[t] = diag_all[inact[t]];
}

__global__ __launch_bounds__(256) void build_D(const float* __restrict__ Daa,
                                               const float* __restrict__ diag_all,
                                               const int* __restrict__ inv,
                                               float* __restrict__ D)
{
    const int e = blockIdx.x * 256 + threadIdx.x;
    const int i = e >> 11, j = e & (NDIM - 1);
    const int ii = inv[i], jj = inv[j];
    float v = 0.f;
    if (ii >= 0 && jj >= 0) v = Daa[ii * HALF + jj];
    if (i == j) v = diag_all[i];
    D[e] = v;
}

__global__ __launch_bounds__(256) void mc_kernel(const float* __restrict__ dm,
                                                 float* __restrict__ mc)
{
    const int e = blockIdx.x * 256 + threadIdx.x;
    const int t = e >> 10, s = e & (HALF - 1);
    mc[e] = (t == s) ? dm[t] : 0.f;
}

__global__ __launch_bounds__(512) void gather_rows(const float* __restrict__ R,
                                                   const int* __restrict__ ridx,
                                                   float* __restrict__ outp)
{
    const int r = blockIdx.x;
    const int c = threadIdx.x * 4;
    *(float4*)(outp + (size_t)r * NDIM + c) =
        *(const float4*)(R + (size_t)ridx[r] * NDIM + c);
}

// ---------------------------------------------------------------------------
extern "C" void kernel_launch(void* const* d_in, const int* in_sizes, int n_in,
                              void* d_out, int out_size, void* d_ws, size_t ws_size,
                              hipStream_t stream)
{
    (void)in_sizes; (void)n_in; (void)out_size; (void)ws_size;
    const float* A     = (const float*)d_in[0];
    const float* O     = (const float*)d_in[1];
    const int*   idx   = (const int*)d_in[2];
    const int*   act   = (const int*)d_in[3];
    const int*   inact = (const int*)d_in[4];

    float* out = (float*)d_out;
    const size_t NN = (size_t)NDIM * NDIM;
    float* A_rec = out;                       // also scratch for P = R@A
    float* right = out + NN;
    float* D     = out + 2 * NN;              // also scratch for W1 (first 8 MB)
    float* mc    = out + 3 * NN;
    float* fc    = mc + (size_t)HALF * HALF;  // Daa
    float* mw    = fc + (size_t)HALF * HALF;
    float* fw    = mw + (size_t)HALF * NDIM;

    char*  w        = (char*)d_ws;
    float* diag_all = (float*)w;              // 2048 f
    float* dm       = (float*)(w + 8192);     // 1024 f
    int*   inv      = (int*)(w + 12288);      // 2048 i

    // 1. right = product of U's (barrier-free single-wave scan, 8 cols/block)
    scan_kernel<<<256, 64, 0, stream>>>(O, idx, right);
    // 2. wavelets (row gathers; fw doubles as Ra, mw as Mi)
    gather_rows<<<1024, 512, 0, stream>>>(right, act, fw);
    gather_rows<<<1024, 512, 0, stream>>>(right, inact, mw);
    // 3. P = R @ A  (A symmetric -> NT, 128-tile)   [into A_rec slot]
    gemm128_nt<<<dim3(16, 16), 256, 0, stream>>>(right, A, A_rec, NDIM, NDIM);
    // 4. diag_all[i] = P[i] . R[i]
    diag_kernel<<<2048, 256, 0, stream>>>(A_rec, right, diag_all);
    // 5. inv map + dm
    prep_kernel<<<1, 1024, 0, stream>>>(act, inact, diag_all, inv, dm);
    // 6. Daa[i,j] = P[a_i] . R[a_j]   [into father_coefficients slot]
    gemm_nt<<<dim3(16, 16), 256, 0, stream>>>(A_rec, NDIM, act, right, NDIM, act,
                                              fc, HALF, NDIM);
    // 7. W1 = Daa @ Ra (=fw)   [into D slot]
    gemm_nn<<<dim3(16, 32), 256, 0, stream>>>(fc, HALF, fw, NDIM, D, NDIM, HALF);
    // 8. A_rec = H^T G (overwrites P — safe, P consumed in 4 & 6)
    arec128<<<dim3(16, 16), 256, 0, stream>>>(fw, mw, D, dm, A_rec);
    // 9. D (overwrites W1 — safe, consumed in 8)
    build_D<<<16384, 256, 0, stream>>>(fc, diag_all, inv, D);
    // 10. mother_coefficients = diag(dm)
    mc_kernel<<<4096, 256, 0, stream>>>(dm, mc);
}

// Round 3
// 724.305 us; speedup vs baseline: 1.4606x; 1.4406x over previous
//
#include <hip/hip_runtime.h>

// Problem constants (N=2048, L=512, K=16, DROP=2, DIM=1024)
#define NDIM 2048
#define LLEV 512
#define KDIM 16
#define HALF 1024

typedef __attribute__((ext_vector_type(8))) short bf16x8;   // 8 bf16 = 4 VGPRs
typedef __attribute__((ext_vector_type(4))) float f32x4;

// ---------------------------------------------------------------------------
// bf16 split helpers: x ~= hi + lo, each RNE bf16 (~16-17 mantissa bits total)
// ---------------------------------------------------------------------------
__device__ inline unsigned short f2bf(float x) {
    unsigned u = __float_as_uint(x);
    u += 0x7fffu + ((u >> 16) & 1u);
    return (unsigned short)(u >> 16);
}
__device__ inline float bf2f(unsigned short b) {
    return __uint_as_float(((unsigned)b) << 16);
}
__device__ inline void split2(float x, unsigned short& h, unsigned short& l) {
    h = f2bf(x);
    l = f2bf(x - bf2f(h));
}

__device__ inline void gl2lds16(const void* g, void* l) {
    __builtin_amdgcn_global_load_lds(
        (const __attribute__((address_space(1))) void*)g,
        (__attribute__((address_space(3))) void*)l, 16, 0, 0);
}

// ---------------------------------------------------------------------------
// Scan kernel (unchanged from R2): right = U_L ... U_1, barrier-free 1-wave.
// ---------------------------------------------------------------------------
__global__ __launch_bounds__(64) void scan_kernel(const float* __restrict__ O,
                                                  const int* __restrict__ idx,
                                                  float* __restrict__ right)
{
    __shared__ float slab[NDIM * 8];
    const int lane = threadIdx.x;
    const int c0 = blockIdx.x * 8;
    const int k  = lane >> 2;
    const int c2 = (lane & 3) * 2;

    for (int r = lane; r < NDIM; r += 64) {
        *(float4*)&slab[r * 8]     = make_float4(0.f, 0.f, 0.f, 0.f);
        *(float4*)&slab[r * 8 + 4] = make_float4(0.f, 0.f, 0.f, 0.f);
    }
    if (lane < 8) slab[(c0 + lane) * 8 + lane] = 1.0f;

    int rows[16]; float a[16]; int wrow;
    #pragma unroll
    for (int j = 0; j < 16; ++j) rows[j] = idx[j];
    {
        const float4* p4 = (const float4*)(O + k * 16);
        #pragma unroll
        for (int q = 0; q < 4; ++q) *(float4*)&a[q * 4] = p4[q];
    }
    wrow = idx[k];

    for (int l = 0; l < LLEV; ++l) {
        int rr[16]; float aa[16];
        const int wr = wrow;
        #pragma unroll
        for (int j = 0; j < 16; ++j) { rr[j] = rows[j]; aa[j] = a[j]; }
        if (l + 1 < LLEV) {
            const int* ip = idx + (l + 1) * 16;
            #pragma unroll
            for (int j = 0; j < 16; ++j) rows[j] = ip[j];
            const float4* p4 = (const float4*)(O + (l + 1) * 256 + k * 16);
            #pragma unroll
            for (int q = 0; q < 4; ++q) *(float4*)&a[q * 4] = p4[q];
            wrow = ip[k];
        }
        float sx = 0.f, sy = 0.f;
        #pragma unroll
        for (int j = 0; j < 16; ++j) {
            float2 v = *(float2*)&slab[rr[j] * 8 + c2];
            sx += aa[j] * v.x;
            sy += aa[j] * v.y;
        }
        *(float2*)&slab[wr * 8 + c2] = make_float2(sx, sy);
    }

    for (int r0 = 0; r0 < NDIM; r0 += 32) {
        const int r = r0 + (lane >> 1);
        const int h = (lane & 1) * 4;
        *(float4*)(right + (size_t)r * NDIM + c0 + h) = *(float4*)&slab[r * 8 + h];
    }
}

// ---------------------------------------------------------------------------
// Split-bf16 MFMA NT gemm: C[m,n] = sum_k A[m,k]*B[n,k] (both row-major, K contig)
// 3-pass: Ah*Bh + Ah*Bl + Al*Bh, fp32 accumulate. 128x128 tile, BK=64.
// LDS layout per tile: [k-chunk(8)][row(128)][8 bf16] -> frag ds_read_b128 are
// 2-way bank aliased only (free), and staging is lane-contiguous for
// global_load_lds (wave-uniform base + lane*16).
// ---------------------------------------------------------------------------
#define GBK 64
__global__ __launch_bounds__(256) void mfma_nt(const unsigned short* __restrict__ Ah,
                                               const unsigned short* __restrict__ Al,
                                               const unsigned short* __restrict__ Bh,
                                               const unsigned short* __restrict__ Bl,
                                               float* __restrict__ C,
                                               int M, int N, int K)
{
    __shared__ unsigned short sA_h[8 * 128 * 8];   // 16 KB each, 64 KB total
    __shared__ unsigned short sA_l[8 * 128 * 8];
    __shared__ unsigned short sB_h[8 * 128 * 8];
    __shared__ unsigned short sB_l[8 * 128 * 8];

    const int tid  = threadIdx.x;
    const int wave = tid >> 6, lane = tid & 63;
    const int lm   = lane & 15, quad = lane >> 4;
    const int wm   = wave & 1,  wn   = wave >> 1;
    const int m0   = blockIdx.x * 128, n0 = blockIdx.y * 128;

    // wave w stages tile w entirely
    const unsigned short* gbase;
    unsigned short* sbase;
    if      (wave == 0) { gbase = Ah + (size_t)m0 * K; sbase = sA_h; }
    else if (wave == 1) { gbase = Al + (size_t)m0 * K; sbase = sA_l; }
    else if (wave == 2) { gbase = Bh + (size_t)n0 * K; sbase = sB_h; }
    else                { gbase = Bl + (size_t)n0 * K; sbase = sB_l; }

    f32x4 acc[4][4];
    #pragma unroll
    for (int i = 0; i < 4; ++i)
        #pragma unroll
        for (int j = 0; j < 4; ++j) acc[i][j] = (f32x4){0.f, 0.f, 0.f, 0.f};

    for (int k0 = 0; k0 < K; k0 += GBK) {
        // stage: 16 global_load_lds per wave (2 row-halves x 8 k-chunks)
        #pragma unroll
        for (int h = 0; h < 2; ++h) {
            const unsigned short* gr = gbase + (size_t)(h * 64 + lane) * K + k0;
            unsigned short* sb = sbase + h * 512;   // 64 rows * 8 elems
            #pragma unroll
            for (int c = 0; c < 8; ++c)
                gl2lds16(gr + c * 8, sb + c * 1024);
        }
        __syncthreads();
        #pragma unroll
        for (int sub = 0; sub < 2; ++sub) {
            const int co = (sub * 4 + quad) * 1024;   // k-chunk element offset
            bf16x8 ah[4], al[4], bh[4], bl[4];
            #pragma unroll
            for (int i = 0; i < 4; ++i) {
                const int m = wm * 64 + i * 16 + lm;
                ah[i] = *(const bf16x8*)&sA_h[co + m * 8];
                al[i] = *(const bf16x8*)&sA_l[co + m * 8];
            }
            #pragma unroll
            for (int j = 0; j < 4; ++j) {
                const int n = wn * 64 + j * 16 + lm;
                bh[j] = *(const bf16x8*)&sB_h[co + n * 8];
                bl[j] = *(const bf16x8*)&sB_l[co + n * 8];
            }
            #pragma unroll
            for (int i = 0; i < 4; ++i)
                #pragma unroll
                for (int j = 0; j < 4; ++j) {
                    acc[i][j] = __builtin_amdgcn_mfma_f32_16x16x32_bf16(ah[i], bh[j], acc[i][j], 0, 0, 0);
                    acc[i][j] = __builtin_amdgcn_mfma_f32_16x16x32_bf16(ah[i], bl[j], acc[i][j], 0, 0, 0);
                    acc[i][j] = __builtin_amdgcn_mfma_f32_16x16x32_bf16(al[i], bh[j], acc[i][j], 0, 0, 0);
                }
        }
        __syncthreads();
    }
    // epilogue: C/D layout col=lane&15, row=quad*4+reg (verified m89/m91)
    #pragma unroll
    for (int i = 0; i < 4; ++i) {
        const int mrow = m0 + wm * 64 + i * 16 + quad * 4;
        #pragma unroll
        for (int j = 0; j < 4; ++j) {
            float* cp = C + (size_t)mrow * N + n0 + wn * 64 + j * 16 + lm;
            #pragma unroll
            for (int r = 0; r < 4; ++r) cp[(size_t)r * N] = acc[i][j][r];
        }
    }
}

// ---------------------------------------------------------------------------
// fp32 -> bf16 hi/lo conversion (optional row gather). 4 floats/thread.
// ---------------------------------------------------------------------------
__global__ __launch_bounds__(256) void conv_hl(const float* __restrict__ src,
                                               const int* __restrict__ gidx,
                                               int kshift,   // log2(row length) for gather
                                               unsigned short* __restrict__ h,
                                               unsigned short* __restrict__ l)
{
    const long e = ((long)blockIdx.x * 256 + threadIdx.x) * 4;
    const float* s;
    if (gidx) {
        const long row = e >> kshift;
        const long col = e - (row << kshift);
        s = src + ((size_t)gidx[row] << kshift) + col;
    } else {
        s = src + e;
    }
    float4 v = *(const float4*)s;
    ushort4 hh, ll;
    split2(v.x, hh.x, ll.x); split2(v.y, hh.y, ll.y);
    split2(v.z, hh.z, ll.z); split2(v.w, hh.w, ll.w);
    *(ushort4*)(h + e) = hh;
    *(ushort4*)(l + e) = ll;
}

// ---------------------------------------------------------------------------
// Transposing fp32 -> bf16 hi/lo: dst[k][m] = src[m][k]. 64x64 LDS tile.
// ---------------------------------------------------------------------------
__global__ __launch_bounds__(256) void tconv_hl(const float* __restrict__ src,
                                                int Msrc, int Ksrc,
                                                unsigned short* __restrict__ h,
                                                unsigned short* __restrict__ l)
{
    __shared__ float t[64][65];
    const int bi = blockIdx.x, bj = blockIdx.y;
    const int tx = threadIdx.x & 15, ty = threadIdx.x >> 4;
    #pragma unroll
    for (int r = 0; r < 4; ++r) {
        const int row = bi * 64 + ty + r * 16;
        float4 v = *(const float4*)(src + (size_t)row * Ksrc + bj * 64 + tx * 4);
        t[ty + r * 16][tx * 4 + 0] = v.x; t[ty + r * 16][tx * 4 + 1] = v.y;
        t[ty + r * 16][tx * 4 + 2] = v.z; t[ty + r * 16][tx * 4 + 3] = v.w;
    }
    __syncthreads();
    #pragma unroll
    for (int r = 0; r < 4; ++r) {
        const int drow = bj * 64 + ty + r * 16;
        ushort4 hh, ll;
        split2(t[tx * 4 + 0][ty + r * 16], hh.x, ll.x);
        split2(t[tx * 4 + 1][ty + r * 16], hh.y, ll.y);
        split2(t[tx * 4 + 2][ty + r * 16], hh.z, ll.z);
        split2(t[tx * 4 + 3][ty + r * 16], hh.w, ll.w);
        *(ushort4*)(h + (size_t)drow * Msrc + bi * 64 + tx * 4) = hh;
        *(ushort4*)(l + (size_t)drow * Msrc + bi * 64 + tx * 4) = ll;
    }
}

// ---------------------------------------------------------------------------
// GT[n,r] = Gfull[r,n] transposed+converted, Gfull fused on the fly:
//   Gfull[r,:] = active(r) ? W1[inva[r],:] : dmrow[r]*right[r,:]
// ---------------------------------------------------------------------------
__global__ __launch_bounds__(256) void gt_build(const float* __restrict__ W1,
                                                const float* __restrict__ right,
                                                const int* __restrict__ inva,
                                                const float* __restrict__ dmrow,
                                                unsigned short* __restrict__ h,
                                                unsigned short* __restrict__ l)
{
    __shared__ float t[64][65];
    const int bi = blockIdx.x, bj = blockIdx.y;
    const int tx = threadIdx.x & 15, ty = threadIdx.x >> 4;
    #pragma unroll
    for (int rr = 0; rr < 4; ++rr) {
        const int r = bi * 64 + ty + rr * 16;
        const int ia = inva[r];
        float4 v;
        if (ia >= 0) {
            v = *(const float4*)(W1 + (size_t)ia * NDIM + bj * 64 + tx * 4);
        } else {
            v = *(const float4*)(right + (size_t)r * NDIM + bj * 64 + tx * 4);
            const float s = dmrow[r];
            v.x *= s; v.y *= s; v.z *= s; v.w *= s;
        }
        t[ty + rr * 16][tx * 4 + 0] = v.x; t[ty + rr * 16][tx * 4 + 1] = v.y;
        t[ty + rr * 16][tx * 4 + 2] = v.z; t[ty + rr * 16][tx * 4 + 3] = v.w;
    }
    __syncthreads();
    #pragma unroll
    for (int rr = 0; rr < 4; ++rr) {
        const int drow = bj * 64 + ty + rr * 16;
        ushort4 hh, ll;
        split2(t[tx * 4 + 0][ty + rr * 16], hh.x, ll.x);
        split2(t[tx * 4 + 1][ty + rr * 16], hh.y, ll.y);
        split2(t[tx * 4 + 2][ty + rr * 16], hh.z, ll.z);
        split2(t[tx * 4 + 3][ty + rr * 16], hh.w, ll.w);
        *(ushort4*)(h + (size_t)drow * NDIM + bi * 64 + tx * 4) = hh;
        *(ushort4*)(l + (size_t)drow * NDIM + bi * 64 + tx * 4) = ll;
    }
}

// ---------------------------------------------------------------------------
// Small helpers
// ---------------------------------------------------------------------------
__global__ __launch_bounds__(256) void diag_kernel(const float* __restrict__ P,
                                                   const float* __restrict__ R,
                                                   float* __restrict__ diag_all)
{
    __shared__ float red[256];
    const int i = blockIdx.x;
    const float4* p4 = (const float4*)(P + (size_t)i * NDIM);
    const float4* r4 = (const float4*)(R + (size_t)i * NDIM);
    float s = 0.f;
    for (int kq = threadIdx.x; kq < NDIM / 4; kq += 256) {
        float4 a = p4[kq], b = r4[kq];
        s += a.x * b.x + a.y * b.y + a.z * b.z + a.w * b.w;
    }
    red[threadIdx.x] = s;
    __syncthreads();
    for (int off = 128; off > 0; off >>= 1) {
        if (threadIdx.x < off) red[threadIdx.x] += red[threadIdx.x + off];
        __syncthreads();
    }
    if (threadIdx.x == 0) diag_all[i] = red[0];
}

__global__ void prep2_kernel(const int* __restrict__ act, const int* __restrict__ inact,
                             const float* __restrict__ diag_all,
                             int* __restrict__ inva, float* __restrict__ dm,
                             float* __restrict__ dmrow)
{
    const int t = threadIdx.x;   // 1024 threads
    inva[t] = -1;
    inva[t + HALF] = -1;
    __syncthreads();
    inva[act[t]] = t;
    const int ir = inact[t];
    const float dv = diag_all[ir];
    dm[t] = dv;
    dmrow[ir] = dv;
}

__global__ __launch_bounds__(256) void build_D(const float* __restrict__ Daa,
                                               const float* __restrict__ diag_all,
                                               const int* __restrict__ inva,
                                               float* __restrict__ D)
{
    const int e = blockIdx.x * 256 + threadIdx.x;
    const int i = e >> 11, j = e & (NDIM - 1);
    const int ii = inva[i], jj = inva[j];
    float v = 0.f;
    if (ii >= 0 && jj >= 0) v = Daa[ii * HALF + jj];
    if (i == j) v = diag_all[i];
    D[e] = v;
}

__global__ __launch_bounds__(256) void mc_kernel(const float* __restrict__ dm,
                                                 float* __restrict__ mc)
{
    const int e = blockIdx.x * 256 + threadIdx.x;
    const int t = e >> 10, s = e & (HALF - 1);
    mc[e] = (t == s) ? dm[t] : 0.f;
}

__global__ __launch_bounds__(512) void gather_rows(const float* __restrict__ R,
                                                   const int* __restrict__ ridx,
                                                   float* __restrict__ outp)
{
    const int r = blockIdx.x;
    const int c = threadIdx.x * 4;
    *(float4*)(outp + (size_t)r * NDIM + c) =
        *(const float4*)(R + (size_t)ridx[r] * NDIM + c);
}

// ---------------------------------------------------------------------------
// fp32 fallback gemms (used only if ws_size is too small for bf16 scratch)
// ---------------------------------------------------------------------------
__global__ __launch_bounds__(256) void gemm_nt64(const float* __restrict__ A, int lda,
                                                 const int* __restrict__ ridxA,
                                                 const float* __restrict__ B, int ldb,
                                                 const int* __restrict__ ridxB,
                                                 float* __restrict__ C, int ldc, int Kk)
{
    __shared__ float As[16][68];
    __shared__ float Bs[16][68];
    const int tid = threadIdx.x;
    const int tx = tid & 15, ty = tid >> 4;
    const int m0 = blockIdx.x * 64, n0 = blockIdx.y * 64;
    const int li = tid >> 2;
    const int lk = (tid & 3) * 4;
    int rowA = m0 + li; if (ridxA) rowA = ridxA[rowA];
    int rowB = n0 + li; if (ridxB) rowB = ridxB[rowB];
    const float* pA = A + (size_t)rowA * lda + lk;
    const float* pB = B + (size_t)rowB * ldb + lk;
    float acc[4][4] = {};
    for (int k0 = 0; k0 < Kk; k0 += 16) {
        float4 a4 = *(const float4*)(pA + k0);
        float4 b4 = *(const float4*)(pB + k0);
        As[lk + 0][li] = a4.x; As[lk + 1][li] = a4.y; As[lk + 2][li] = a4.z; As[lk + 3][li] = a4.w;
        Bs[lk + 0][li] = b4.x; Bs[lk + 1][li] = b4.y; Bs[lk + 2][li] = b4.z; Bs[lk + 3][li] = b4.w;
        __syncthreads();
        #pragma unroll
        for (int kk = 0; kk < 16; ++kk) {
            float4 av = *(const float4*)&As[kk][ty * 4];
            float4 bv = *(const float4*)&Bs[kk][tx * 4];
            float a[4] = {av.x, av.y, av.z, av.w};
            float b[4] = {bv.x, bv.y, bv.z, bv.w};
            #pragma unroll
            for (int i = 0; i < 4; ++i)
                #pragma unroll
                for (int j = 0; j < 4; ++j) acc[i][j] += a[i] * b[j];
        }
        __syncthreads();
    }
    #pragma unroll
    for (int i = 0; i < 4; ++i) {
        float4 v = make_float4(acc[i][0], acc[i][1], acc[i][2], acc[i][3]);
        *(float4*)(C + (size_t)(m0 + ty * 4 + i) * ldc + n0 + tx * 4) = v;
    }
}

__global__ __launch_bounds__(256) void gemm_nn64(const float* __restrict__ A, int lda,
                                                 const float* __restrict__ B, int ldb,
                                                 float* __restrict__ C, int ldc, int Kk)
{
    __shared__ float As[16][68];
    __shared__ float Bs[16][68];
    const int tid = threadIdx.x;
    const int tx = tid & 15, ty = tid >> 4;
    const int m0 = blockIdx.x * 64, n0 = blockIdx.y * 64;
    const int li = tid >> 2;
    const int lk = (tid & 3) * 4;
    const int bk = tid >> 4;
    const int bn = (tid & 15) * 4;
    const float* pA = A + (size_t)(m0 + li) * lda + lk;
    float acc[4][4] = {};
    for (int k0 = 0; k0 < Kk; k0 += 16) {
        float4 a4 = *(const float4*)(pA + k0);
        float4 b4 = *(const float4*)(B + (size_t)(k0 + bk) * ldb + n0 + bn);
        As[lk + 0][li] = a4.x; As[lk + 1][li] = a4.y; As[lk + 2][li] = a4.z; As[lk + 3][li] = a4.w;
        *(float4*)&Bs[bk][bn] = b4;
        __syncthreads();
        #pragma unroll
        for (int kk = 0; kk < 16; ++kk) {
            float4 av = *(const float4*)&As[kk][ty * 4];
            float4 bv = *(const float4*)&Bs[kk][tx * 4];
            float a[4] = {av.x, av.y, av.z, av.w};
            float b[4] = {bv.x, bv.y, bv.z, bv.w};
            #pragma unroll
            for (int i = 0; i < 4; ++i)
                #pragma unroll
                for (int j = 0; j < 4; ++j) acc[i][j] += a[i] * b[j];
        }
        __syncthreads();
    }
    #pragma unroll
    for (int i = 0; i < 4; ++i) {
        float4 v = make_float4(acc[i][0], acc[i][1], acc[i][2], acc[i][3]);
        *(float4*)(C + (size_t)(m0 + ty * 4 + i) * ldc + n0 + tx * 4) = v;
    }
}

__global__ __launch_bounds__(256) void arec64(const float* __restrict__ fw,
                                              const float* __restrict__ mw,
                                              const float* __restrict__ W1,
                                              const float* __restrict__ dm,
                                              float* __restrict__ C)
{
    __shared__ float As[16][68];
    __shared__ float Bs[16][68];
    const int tid = threadIdx.x;
    const int tx = tid & 15, ty = tid >> 4;
    const int m0 = blockIdx.x * 64, n0 = blockIdx.y * 64;
    const int bk = tid >> 4;
    const int bn = (tid & 15) * 4;
    float acc[4][4] = {};
    for (int t0 = 0; t0 < NDIM; t0 += 16) {
        const int t = t0 + bk;
        const float* Hrow; const float* Grow; float gs;
        if (t < HALF) { Hrow = fw + (size_t)t * NDIM; Grow = W1 + (size_t)t * NDIM; gs = 1.f; }
        else          { Hrow = mw + (size_t)(t - HALF) * NDIM; Grow = Hrow; gs = dm[t - HALF]; }
        float4 a4 = *(const float4*)(Hrow + m0 + bn);
        float4 b4 = *(const float4*)(Grow + n0 + bn);
        b4.x *= gs; b4.y *= gs; b4.z *= gs; b4.w *= gs;
        *(float4*)&As[bk][bn] = a4;
        *(float4*)&Bs[bk][bn] = b4;
        __syncthreads();
        #pragma unroll
        for (int kk = 0; kk < 16; ++kk) {
            float4 av = *(const float4*)&As[kk][ty * 4];
            float4 bv = *(const float4*)&Bs[kk][tx * 4];
            float a[4] = {av.x, av.y, av.z, av.w};
            float b[4] = {bv.x, bv.y, bv.z, bv.w};
            #pragma unroll
            for (int i = 0; i < 4; ++i)
                #pragma unroll
                for (int j = 0; j < 4; ++j) acc[i][j] += a[i] * b[j];
        }
        __syncthreads();
    }
    #pragma unroll
    for (int i = 0; i < 4; ++i) {
        float4 v = make_float4(acc[i][0], acc[i][1], acc[i][2], acc[i][3]);
        *(float4*)(C + (size_t)(m0 + ty * 4 + i) * NDIM + n0 + tx * 4) = v;
    }
}

// ---------------------------------------------------------------------------
extern "C" void kernel_launch(void* const* d_in, const int* in_sizes, int n_in,
                              void* d_out, int out_size, void* d_ws, size_t ws_size,
                              hipStream_t stream)
{
    (void)in_sizes; (void)n_in; (void)out_size;
    const float* A     = (const float*)d_in[0];
    const float* O     = (const float*)d_in[1];
    const int*   idx   = (const int*)d_in[2];
    const int*   act   = (const int*)d_in[3];
    const int*   inact = (const int*)d_in[4];

    float* out = (float*)d_out;
    const size_t NN = (size_t)NDIM * NDIM;
    float* A_rec = out;                       // scratch for P = R@A until step 13
    float* right = out + NN;
    float* D     = out + 2 * NN;              // scratch for W1 until build_D
    float* mc    = out + 3 * NN;
    float* fc    = mc + (size_t)HALF * HALF;  // Daa
    float* mw    = fc + (size_t)HALF * HALF;
    float* fw    = mw + (size_t)HALF * NDIM;

    char*  w        = (char*)d_ws;
    float* diag_all = (float*)w;              // 2048 f
    float* dm       = (float*)(w + 8192);     // 1024 f
    int*   inva     = (int*)(w + 12288);      // 2048 i
    float* dmrow    = (float*)(w + 20480);    // 2048 f

    const size_t MB = 1024 * 1024;
    const size_t WS_NEEDED = 65536 + 32 * MB;

    // common prefix
    scan_kernel<<<256, 64, 0, stream>>>(O, idx, right);
    gather_rows<<<1024, 512, 0, stream>>>(right, act, fw);
    gather_rows<<<1024, 512, 0, stream>>>(right, inact, mw);

    if (ws_size >= WS_NEEDED) {
        // bf16 scratch regions
        char* r1 = w + 65536;                 // 16 MB: Rh/Rl -> RTh/RTl
        char* r2 = r1 + 16 * MB;              // 16 MB: Ah/Al -> Pa/F -> D/FT -> GT
        unsigned short* Rh  = (unsigned short*)r1;
        unsigned short* Rl  = (unsigned short*)(r1 + 8 * MB);
        unsigned short* RTh = Rh;   // reuse after P gemm
        unsigned short* RTl = Rl;
        unsigned short* Ah  = (unsigned short*)r2;
        unsigned short* Al  = (unsigned short*)(r2 + 8 * MB);
        unsigned short* Pah = (unsigned short*)r2;             // after P
        unsigned short* Pal = (unsigned short*)(r2 + 4 * MB);
        unsigned short* Fh  = (unsigned short*)(r2 + 8 * MB);
        unsigned short* Fl  = (unsigned short*)(r2 + 12 * MB);
        unsigned short* Dh  = (unsigned short*)r2;             // after Daa
        unsigned short* Dl  = (unsigned short*)(r2 + 2 * MB);
        unsigned short* FTh = (unsigned short*)(r2 + 4 * MB);
        unsigned short* FTl = (unsigned short*)(r2 + 8 * MB);
        unsigned short* GTh = (unsigned short*)r2;             // after W1
        unsigned short* GTl = (unsigned short*)(r2 + 8 * MB);

        // 3. convert R and A to bf16 hi/lo
        conv_hl<<<4096, 256, 0, stream>>>(right, nullptr, 11, Rh, Rl);
        conv_hl<<<4096, 256, 0, stream>>>(A, nullptr, 11, Ah, Al);
        // 4. P = R @ A (A symmetric -> NT)  [A_rec slot]
        mfma_nt<<<dim3(16, 16), 256, 0, stream>>>(Rh, Rl, Ah, Al, A_rec, NDIM, NDIM, NDIM);
        // 5. diag + prep
        diag_kernel<<<2048, 256, 0, stream>>>(A_rec, right, diag_all);
        prep2_kernel<<<1, 1024, 0, stream>>>(act, inact, diag_all, inva, dm, dmrow);
        // 7. Pa = P[act], F = fw in bf16
        conv_hl<<<2048, 256, 0, stream>>>(A_rec, act, 11, Pah, Pal);
        conv_hl<<<2048, 256, 0, stream>>>(fw, nullptr, 11, Fh, Fl);
        // 8. Daa = Pa . F^T  -> fc
        mfma_nt<<<dim3(8, 8), 256, 0, stream>>>(Pah, Pal, Fh, Fl, fc, HALF, HALF, NDIM);
        // 9. Dh/Dl = conv(Daa); FT = fw^T
        conv_hl<<<1024, 256, 0, stream>>>(fc, nullptr, 10, Dh, Dl);
        tconv_hl<<<dim3(16, 32), 256, 0, stream>>>(fw, HALF, NDIM, FTh, FTl);
        // 10. W1 = Daa @ fw  (NT on Daa rows x FT rows)  [D slot]
        mfma_nt<<<dim3(8, 16), 256, 0, stream>>>(Dh, Dl, FTh, FTl, D, HALF, NDIM, HALF);
        // 11. RT = right^T
        tconv_hl<<<dim3(32, 32), 256, 0, stream>>>(right, NDIM, NDIM, RTh, RTl);
        // 12. GT[n,r] = Gfull[r,n], Gfull fused from W1 / dm*right
        gt_build<<<dim3(32, 32), 256, 0, stream>>>(D, right, inva, dmrow, GTh, GTl);
        // 13. A_rec = RT . GT^T (= R^T Gfull)   [overwrites P]
        mfma_nt<<<dim3(16, 16), 256, 0, stream>>>(RTh, RTl, GTh, GTl, A_rec, NDIM, NDIM, NDIM);
        // 14. D output
        build_D<<<16384, 256, 0, stream>>>(fc, diag_all, inva, D);
        // 15. mother_coefficients = diag(dm)
        mc_kernel<<<4096, 256, 0, stream>>>(dm, mc);
    } else {
        // fp32 fallback (R1 structure)
        gemm_nt64<<<dim3(32, 32), 256, 0, stream>>>(right, NDIM, nullptr, A, NDIM, nullptr,
                                                    A_rec, NDIM, NDIM);
        diag_kernel<<<2048, 256, 0, stream>>>(A_rec, right, diag_all);
        prep2_kernel<<<1, 1024, 0, stream>>>(act, inact, diag_all, inva, dm, dmrow);
        gemm_nt64<<<dim3(16, 16), 256, 0, stream>>>(A_rec, NDIM, act, right, NDIM, act,
                                                    fc, HALF, NDIM);
        gemm_nn64<<<dim3(16, 32), 256, 0, stream>>>(fc, HALF, fw, NDIM, D, NDIM, HALF);
        arec64<<<dim3(32, 32), 256, 0, stream>>>(fw, mw, D, dm, A_rec);
        build_D<<<16384, 256, 0, stream>>>(fc, diag_all, inva, D);
        mc_kernel<<<4096, 256, 0, stream>>>(dm, mc);
    }
}